// Round 1
// 150.193 us; speedup vs baseline: 1.0025x; 1.0025x over previous
//
#include <hip/hip_runtime.h>
#include <hip/hip_bf16.h>

#define NB 8
#define ND 768
#define NCH 3
#define NMIX 5
#define NH 10
#define NS 10

#define PI2F 6.283185307179586f
#define HALF_PI2SQ 19.739208802178716f   // 0.5 * (2*pi)^2
#define ZITTERF 1e-4f

// Lookup table for the weighted kernel function g_bc(|dx|):
//   g_bc(dx) = sum_m w[b,c,m] * exp(ce_m*dx^2) * cos(2*pi*mu_m*dx)   (even in dx)
// 6144 points over [0,12]; linear interp error <= h^2*|g''|/8 ~ 6e-5.
#define TAB_N 6144
#define TAB_MAXX 12.0f
#define CROWS 12                          // output rows per block in kernel C

// cos(2*pi*t) via hardware v_cos (input in revolutions), with fract range-reduction
__device__ __forceinline__ float cos2pi(float t) {
    return __builtin_amdgcn_cosf(__builtin_amdgcn_fractf(t));
}

// ---------------------------------------------------------------------------
// Kernel A: feature[b,i,c,m] = sum_j K[b,m,i,j,c]*yc[b,j,c]; writes tif[b,i,c,0..5]
// One wave (64 lanes) per (b,i,c) row; lanes stride over j; shfl reduction.
// (unchanged — exact math; feature errors are x10-amplified through the softmax)
// ---------------------------------------------------------------------------
__global__ void __launch_bounds__(256) feature_kernel(
        const float* __restrict__ xc, const float* __restrict__ yc,
        const float* __restrict__ mu, const float* __restrict__ istd,
        float* __restrict__ tif) {
    const int wid  = (blockIdx.x << 2) + (threadIdx.x >> 6);
    const int lane = threadIdx.x & 63;
    const int b   = wid / (ND * NCH);
    const int rem = wid % (ND * NCH);
    const int i = rem / NCH;
    const int c = rem % NCH;

    float cmu[NMIX], cexp[NMIX];
#pragma unroll
    for (int m = 0; m < NMIX; ++m) {
        const float is = istd[m];
        cmu[m]  = mu[m];
        cexp[m] = -HALF_PI2SQ * is * is;
    }

    const float xi = xc[(b * ND + i) * NCH + c];
    float acc[NMIX] = {0.f, 0.f, 0.f, 0.f, 0.f};

    for (int j = lane; j < ND; j += 64) {
        const float xj = xc[(b * ND + j) * NCH + c];
        const float yj = yc[(b * ND + j) * NCH + c];
        const float dx  = xi - xj;
        const float dx2 = dx * dx;
#pragma unroll
        for (int m = 0; m < NMIX; ++m) {
            const float e  = __expf(cexp[m] * dx2);
            const float co = cos2pi(cmu[m] * dx);
            acc[m] += e * co * yj;
        }
    }

#pragma unroll
    for (int m = 0; m < NMIX; ++m)
        for (int off = 32; off; off >>= 1)
            acc[m] += __shfl_down(acc[m], off);

    if (lane == 0) {
        const float yi = yc[(b * ND + i) * NCH + c];
        float* tp = tif + ((b * ND + i) * NCH + c) * (NMIX + 1);
#pragma unroll
        for (int m = 0; m < NMIX; ++m) tp[m] = acc[m] + ZITTERF * yi;
        tp[NMIX] = yi;
    }
}

// ---------------------------------------------------------------------------
// Kernel B: per-batch MLP + Gumbel-softmax -> w[b, c*5+m], then builds the
// per-(b,c) combined LUT for kernel C (w is already resident in LDS here).
// One block per batch.
// ---------------------------------------------------------------------------
__global__ void __launch_bounds__(256) mlp_gumbel_kernel(
        const float* __restrict__ tif,
        const float* __restrict__ W1, const float* __restrict__ b1,
        const float* __restrict__ W2, const float* __restrict__ b2,
        const float* __restrict__ W3, const float* __restrict__ b3,
        const float* __restrict__ W4, const float* __restrict__ b4,
        const float* __restrict__ W5, const float* __restrict__ b5,
        const float* __restrict__ unif,
        const float* __restrict__ mu, const float* __restrict__ istd,
        float* __restrict__ wout, float* __restrict__ gtab) {
    const int b   = blockIdx.x;
    const int tid = threadIdx.x;

    __shared__ float sW1[NH * 6], sb1[NH];
    __shared__ float red[4][NCH * NH];
    __shared__ float hvec[NCH * NH], h2[NH], h3[NH], h4[NH], ll[NCH * NMIX], wacc[NCH * NMIX];

    if (tid < NH * 6) sW1[tid] = W1[tid];
    if (tid < NH)     sb1[tid] = b1[tid];
    if (tid < NCH * NMIX) wacc[tid] = 0.f;
    __syncthreads();

    float part[NCH * NH];
#pragma unroll
    for (int t = 0; t < NCH * NH; ++t) part[t] = 0.f;

    for (int ii = tid; ii < ND; ii += 256) {
        for (int c = 0; c < NCH; ++c) {
            const float* tp = tif + ((b * ND + ii) * NCH + c) * (NMIX + 1);
            float f[6];
#pragma unroll
            for (int m = 0; m < 6; ++m) f[m] = tp[m];
#pragma unroll
            for (int k = 0; k < NH; ++k) {
                float a = sb1[k];
#pragma unroll
                for (int m = 0; m < 6; ++m) a += f[m] * sW1[k * 6 + m];
                part[c * NH + k] += fmaxf(a, 0.f);
            }
        }
    }

#pragma unroll
    for (int t = 0; t < NCH * NH; ++t)
        for (int off = 32; off; off >>= 1)
            part[t] += __shfl_down(part[t], off);

    const int lane = tid & 63, wv = tid >> 6;
    if (lane == 0)
        for (int t = 0; t < NCH * NH; ++t) red[wv][t] = part[t];
    __syncthreads();

    if (tid < NCH * NH)
        hvec[tid] = (red[0][tid] + red[1][tid] + red[2][tid] + red[3][tid]) * (1.f / (float)ND);
    __syncthreads();

    if (tid < NH) {
        float a = b2[tid];
        for (int j = 0; j < NCH * NH; ++j) a += W2[tid * (NCH * NH) + j] * hvec[j];
        h2[tid] = fmaxf(a, 0.f);
    }
    __syncthreads();
    if (tid < NH) {
        float a = b3[tid];
        for (int j = 0; j < NH; ++j) a += W3[tid * NH + j] * h2[j];
        h3[tid] = fmaxf(a, 0.f);
    }
    __syncthreads();
    if (tid < NH) {
        float a = b4[tid];
        for (int j = 0; j < NH; ++j) a += W4[tid * NH + j] * h3[j];
        h4[tid] = fmaxf(a, 0.f);
    }
    __syncthreads();
    if (tid < NCH * NMIX) {
        float a = b5[tid];
        for (int j = 0; j < NH; ++j) a += W5[tid * NH + j] * h4[j];
        ll[tid] = a;
    }
    __syncthreads();

    // Gumbel-softmax: threads 0..29 handle (s, c) pairs; mean over ns=10 samples
    if (tid < NS * NCH) {
        const int s = tid / NCH, c = tid % NCH;
        float z[NMIX], zmax = -1e30f;
#pragma unroll
        for (int m = 0; m < NMIX; ++m) {
            const float u = unif[((b * NS + s) * NCH + c) * NMIX + m];
            const float g = -__logf(-__logf(u + 1e-20f));
            z[m] = (g + ll[c * NMIX + m]) * 10.0f;   // / TEMP(=0.1)
            zmax = fmaxf(zmax, z[m]);
        }
        float e[NMIX], se = 0.f;
#pragma unroll
        for (int m = 0; m < NMIX; ++m) { e[m] = __expf(z[m] - zmax); se += e[m]; }
        const float inv = 0.1f / se;  // 1/sum * 1/ns
#pragma unroll
        for (int m = 0; m < NMIX; ++m)
            atomicAdd(&wacc[c * NMIX + m], e[m] * inv);
    }
    __syncthreads();
    if (tid < NCH * NMIX) wout[b * (NCH * NMIX) + tid] = wacc[tid];

    // ---- build combined LUT: gtab[b][c][idx] = sum_m wacc[c,m]*exp(..)*cos(..)
    float bmu[NMIX], bce[NMIX];
#pragma unroll
    for (int m = 0; m < NMIX; ++m) {
        const float is = istd[m];
        bmu[m] = mu[m];
        bce[m] = -HALF_PI2SQ * is * is;
    }
    float* gt = gtab + (size_t)b * NCH * TAB_N;
    const float step = TAB_MAXX / (float)(TAB_N - 1);
    for (int idx = tid; idx < TAB_N; idx += 256) {
        const float dxv = (float)idx * step;
        const float dx2 = dxv * dxv;
        float eco[NMIX];
#pragma unroll
        for (int m = 0; m < NMIX; ++m)
            eco[m] = __expf(bce[m] * dx2) * cos2pi(bmu[m] * dxv);
#pragma unroll
        for (int c = 0; c < NCH; ++c) {
            float v = 0.f;
#pragma unroll
            for (int m = 0; m < NMIX; ++m) v += wacc[c * NMIX + m] * eco[m];
            gt[c * TAB_N + idx] = v;
        }
    }
}

// ---------------------------------------------------------------------------
// Kernel C: weighted[b,i,j,c] = g_bc(|x_i - x_j|) (+diag) via LDS LUT + lerp.
// Block = (b, 12-row band); stages the 3 per-channel tables (72 KB) in LDS.
// 512 blocks = exactly 2 resident blocks/CU. Write-bound by design.
// ---------------------------------------------------------------------------
__global__ void __launch_bounds__(256) weighted_lut_kernel(
        const float* __restrict__ xc, const float* __restrict__ gtab,
        const float* __restrict__ likerr, float* __restrict__ out) {
    const int b   = blockIdx.x / (ND / CROWS);
    const int i0  = (blockIdx.x % (ND / CROWS)) * CROWS;
    const int tid = threadIdx.x;

    __shared__ float stab[NCH * TAB_N];    // 72 KB
    __shared__ float sxi[CROWS][NCH];
    __shared__ float sdiag[NCH];

    // stage tables (float4, 18 iters/thread)
    const float4* gt4 = (const float4*)(gtab + (size_t)b * NCH * TAB_N);
    float4* st4 = (float4*)stab;
    for (int t = tid; t < (NCH * TAB_N) / 4; t += 256) st4[t] = gt4[t];

    if (tid < CROWS * NCH)
        sxi[tid / NCH][tid % NCH] = xc[(b * ND + i0 + tid / NCH) * NCH + (tid % NCH)];
    if (tid < NCH) {
        const float lk = fminf(fmaxf(likerr[tid], 0.1f), 1.0f);
        sdiag[tid] = ZITTERF + lk * lk;
    }
    __syncthreads();

    const float scale = (float)(TAB_N - 1) / TAB_MAXX;
    for (int jj = tid; jj < ND; jj += 256) {            // 3 iterations
        float xj[NCH];
#pragma unroll
        for (int c = 0; c < NCH; ++c) xj[c] = xc[(b * ND + jj) * NCH + c];
#pragma unroll
        for (int r = 0; r < CROWS; ++r) {
            const int i = i0 + r;
            float res[NCH];
#pragma unroll
            for (int c = 0; c < NCH; ++c) {
                const float dx = sxi[r][c] - xj[c];
                float u = fabsf(dx) * scale;
                u = fminf(u, (float)TAB_N - 1.001f);    // safety clamp (|dx|<=~9)
                const int   iu = (int)u;
                const float fr = u - (float)iu;
                const float t0 = stab[c * TAB_N + iu];
                const float t1 = stab[c * TAB_N + iu + 1];
                res[c] = fmaf(t1 - t0, fr, t0);
            }
            if (i == jj) {
                res[0] += sdiag[0]; res[1] += sdiag[1]; res[2] += sdiag[2];
            }
            float* op = out + (size_t)((b * ND + i) * ND + jj) * NCH;
            op[0] = res[0]; op[1] = res[1]; op[2] = res[2];
        }
    }
}

extern "C" void kernel_launch(void* const* d_in, const int* in_sizes, int n_in,
                              void* d_out, int out_size, void* d_ws, size_t ws_size,
                              hipStream_t stream) {
    const float* xc     = (const float*)d_in[0];
    const float* yc     = (const float*)d_in[1];
    const float* mu     = (const float*)d_in[2];
    const float* istd   = (const float*)d_in[3];
    const float* likerr = (const float*)d_in[4];
    const float* unif   = (const float*)d_in[5];
    const float* W1 = (const float*)d_in[6];  const float* b1 = (const float*)d_in[7];
    const float* W2 = (const float*)d_in[8];  const float* b2 = (const float*)d_in[9];
    const float* W3 = (const float*)d_in[10]; const float* b3 = (const float*)d_in[11];
    const float* W4 = (const float*)d_in[12]; const float* b4 = (const float*)d_in[13];
    const float* W5 = (const float*)d_in[14]; const float* b5 = (const float*)d_in[15];

    float* out  = (float*)d_out;
    float* tif  = (float*)d_ws;                       // NB*ND*NCH*6 = 110592 floats
    float* wmix = tif + NB * ND * NCH * (NMIX + 1);   // NB*15 = 120 floats
    float* gtab = wmix + NB * NCH * NMIX;             // NB*NCH*TAB_N = 147456 floats (16B-aligned)

    // A: one wave per (b,i,c) -> 8*768*3 = 18432 waves = 4608 blocks
    feature_kernel<<<(NB * ND * NCH) / 4, 256, 0, stream>>>(xc, yc, mu, istd, tif);

    // B: one block per batch (also builds the 24 combined LUTs)
    mlp_gumbel_kernel<<<NB, 256, 0, stream>>>(tif, W1, b1, W2, b2, W3, b3, W4, b4,
                                              W5, b5, unif, mu, istd, wmix, gtab);

    // C: LUT-based weighted sum; 8 * (768/12) = 512 blocks
    weighted_lut_kernel<<<NB * (ND / CROWS), 256, 0, stream>>>(xc, gtab, likerr, out);
}